// Round 17
// baseline (69.285 us; speedup 1.0000x reference)
//
#include <hip/hip_runtime.h>
#include <math.h>

#define NUM_EMB 512
#define DIMV 65          // 65
#define DD   64          // DIM-1
#define BB   2048
#define NN   256
#define TILEF 1040       // 16 rows x 65 floats per tile
#define WTILES 8         // tiles per wave (wave owns 128 rows = half a b)
#define GRID_APPLY ((BB * NN) / (128 * 4))   // 1024 blocks (4 waves each)

typedef short short8 __attribute__((ext_vector_type(8)));   // 8 bf16 (4 VGPR)
typedef float f32x4  __attribute__((ext_vector_type(4)));   // MFMA acc
typedef float fv4    __attribute__((ext_vector_type(4)));   // ext-vector float4
                                                            // (nt-store compatible)

__device__ __forceinline__ float gelu_exact(float x) {
    return 0.5f * x * (1.0f + erff(x * 0.7071067811865475f));
}

// fp32 -> bf16, round-to-nearest-even, deterministic
__device__ __forceinline__ unsigned f2bf_u(float f) {
    unsigned u = __builtin_bit_cast(unsigned, f);
    u += 0x7FFFu + ((u >> 16) & 1u);
    return u >> 16;
}
__device__ __forceinline__ unsigned short f2bf(float f) {
    return (unsigned short)f2bf_u(f);
}

// ---------------------------------------------------------------------------
// Kernel 1: build W[e] = H0 @ ... @ H63 (Householder matvec + rank-1 update),
// scale last column, store TRANSPOSED bf16: WgT[e][c][d] = bf16(W[e][d][c]).
// Echoes r_idx into the out tail.
// ---------------------------------------------------------------------------
__global__ __launch_bounds__(256) void build_W(const float* __restrict__ emb,
                                               const float* __restrict__ flip_sign,
                                               const int*   __restrict__ r_idx,
                                               unsigned short* __restrict__ WgT,
                                               float* __restrict__ out) {
    __shared__ float v_lds[DD * DD];
    __shared__ float s_lds[DD];
    const int e = blockIdx.x;
    const int t = threadIdx.x;
    const int r = t >> 2;
    const int q = t & 3;

    const float* erow = emb + (size_t)e * (DD * DD);
    #pragma unroll
    for (int p = 0; p < 16; ++p) {
        int idx = p * 256 + t;
        v_lds[idx] = gelu_exact(erow[idx]);
    }

    // r_idx passthrough: output 1 lives at out[BB*NN*DIMV + b]
    if (t < 4) {
        int bi = e * 4 + t;
        out[(size_t)BB * NN * DIMV + bi] = (float)r_idx[bi];
    }
    __syncthreads();

    {
        const float* vr = &v_lds[r * DD + q * 16];
        float ss = 0.f;
        #pragma unroll
        for (int k = 0; k < 16; ++k) ss += vr[k] * vr[k];
        ss += __shfl_xor(ss, 1);
        ss += __shfl_xor(ss, 2);
        if (q == 0) s_lds[r] = 2.0f / ss;
    }
    __syncthreads();

    float Wq[16];
    #pragma unroll
    for (int k = 0; k < 16; ++k) Wq[k] = ((q * 16 + k) == r) ? 1.0f : 0.0f;

    float vv[16], nv[16];
    {
        const float* vr = &v_lds[q * 16];
        *(float4*)&nv[0]  = *(const float4*)&vr[0];
        *(float4*)&nv[4]  = *(const float4*)&vr[4];
        *(float4*)&nv[8]  = *(const float4*)&vr[8];
        *(float4*)&nv[12] = *(const float4*)&vr[12];
    }

    for (int w = 0; w < DD; ++w) {
        #pragma unroll
        for (int k = 0; k < 16; ++k) vv[k] = nv[k];
        if (w < DD - 1) {
            const float* vr = &v_lds[(w + 1) * DD + q * 16];
            *(float4*)&nv[0]  = *(const float4*)&vr[0];
            *(float4*)&nv[4]  = *(const float4*)&vr[4];
            *(float4*)&nv[8]  = *(const float4*)&vr[8];
            *(float4*)&nv[12] = *(const float4*)&vr[12];
        }
        float p0 = Wq[0] * vv[0],  p1 = Wq[1] * vv[1];
        float p2 = Wq[2] * vv[2],  p3 = Wq[3] * vv[3];
        #pragma unroll
        for (int k = 4; k < 16; k += 4) {
            p0 += Wq[k]     * vv[k];
            p1 += Wq[k + 1] * vv[k + 1];
            p2 += Wq[k + 2] * vv[k + 2];
            p3 += Wq[k + 3] * vv[k + 3];
        }
        float p = (p0 + p1) + (p2 + p3);
        p += __shfl_xor(p, 1);
        p += __shfl_xor(p, 2);
        const float sc = s_lds[w] * p;
        #pragma unroll
        for (int k = 0; k < 16; ++k) Wq[k] -= sc * vv[k];
    }

    if (q == 3) Wq[15] *= flip_sign[0];

    // store transposed bf16: WgT[e][c][d] with c = 16q+k, d = r
    unsigned short* wd = WgT + (size_t)e * (DD * DD) + r;
    #pragma unroll
    for (int k = 0; k < 16; ++k)
        wd[(16 * q + k) * DD] = f2bf(Wq[k]);
}

// ---------------------------------------------------------------------------
// Kernel 2 (MFMA + DMA + NT stores + TRIPLE-buffered 2-ahead pipeline):
//   out[.,0]=x[.,0]; out[.,1+c]=sum_d x[.,1+d]*W[d][c]
// R17 change vs R16: loads issued TWO tiles ahead into buf (i%3), and the
// counted vmcnt gives NT stores two full tiles of retire slack. gfx9 vmcnt
// retires IN ORDER and is shared by loads+stores; NT stores ack beyond L2
// (slow), so R16's vmcnt(10) implicitly waited on S(i-1) -> serialized.
// Now newer-than-L(i) = S(i-2):5 + L(i+1):5 + S(i-1):5 + L(i+2):5 ->
// vmcnt(20) steady state: no wait on any store younger than 2 tiles.
//   waits: i0:10, i1:15, i2..5:20, i6:15, i7:10.
// Race: L(i+3) (next writer of buf[i%3]) issues after tile i's ds_reads
// returned (lgkmcnt-ordered before S(i) stores). LDS 49920 B -> 3 blk/CU.
// ---------------------------------------------------------------------------
__global__ __launch_bounds__(256) void apply_W(const float* __restrict__ x,
                                               const int*   __restrict__ r_idx,
                                               const unsigned short* __restrict__ WgT,
                                               float* __restrict__ out) {
    __shared__ alignas(16) float IMG[4][3 * TILEF];   // 4 waves x 12480 B
    const int t = threadIdx.x;
    const int w = t >> 6;
    const int l = t & 63;
    const int lrow  = l & 15;
    const int kslot = l >> 4;

    const int    gw   = blockIdx.x * 4 + w;       // global wave id (< 4096)
    const size_t row0 = (size_t)gw * 128;         // wave's 128 rows
    const int    b    = gw >> 1;                  // half-b per wave

    const int e = r_idx[b];                       // uniform scalar
    float* img = IMG[w];
    const float* xw = x   + row0 * DIMV;          // 8320 floats (8 tiles)
    float*       ow = out + row0 * DIMV;

    // ---- B fragments (VGPR loads, 8KB table, L2/L3-hot) ----
    const unsigned short* wb = WgT + (size_t)e * (DD * DD);
    short8 bfrg[4][2];
    #pragma unroll
    for (int ct = 0; ct < 4; ++ct)
        #pragma unroll
        for (int kb = 0; kb < 2; ++kb)
            bfrg[ct][kb] = *(const short8*)(wb + (ct * 16 + lrow) * DD + kb * 32 + kslot * 8);

    // ---- DMA issue: 5 async loads of tile i into buf (i%3) ----
    auto issue_loads = [&](int i) {
        const float* g = xw + (size_t)i * TILEF;
        float* d = img + (i % 3) * TILEF;
        __builtin_amdgcn_global_load_lds((const unsigned*)(g + 0   + 4 * l), (unsigned*)(d + 0),    16, 0, 0);
        __builtin_amdgcn_global_load_lds((const unsigned*)(g + 256 + 4 * l), (unsigned*)(d + 256),  16, 0, 0);
        __builtin_amdgcn_global_load_lds((const unsigned*)(g + 512 + 4 * l), (unsigned*)(d + 512),  16, 0, 0);
        __builtin_amdgcn_global_load_lds((const unsigned*)(g + 768 + 4 * l), (unsigned*)(d + 768),  16, 0, 0);
        if (l < 4)   // 64B tail (floats 1024..1039)
            __builtin_amdgcn_global_load_lds((const unsigned*)(g + 1024 + 4 * l), (unsigned*)(d + 1024), 16, 0, 0);
    };

    // ---- compute + store one tile (buffer i%3 is DMA-complete) ----
    auto do_tile = [&](int i) {
        const float* buf = img + (i % 3) * TILEF;
        // A fragments: 8 b32 LDS reads per kb (<=2-way bank = free)
        short8 afrg[2];
        #pragma unroll
        for (int kb = 0; kb < 2; ++kb) {
            const float* xp = buf + lrow * DIMV + 1 + kb * 32 + kslot * 8;
            union { short8 s; unsigned u[4]; } af;
            #pragma unroll
            for (int jj = 0; jj < 4; ++jj)
                af.u[jj] = f2bf_u(xp[2 * jj]) | (f2bf_u(xp[2 * jj + 1]) << 16);
            afrg[kb] = af.s;
        }

        // 8 MFMAs (4 col-tiles x K=64)
        f32x4 acc[4];
        #pragma unroll
        for (int ct = 0; ct < 4; ++ct) {
            f32x4 c0 = {0.f, 0.f, 0.f, 0.f};
            c0 = __builtin_amdgcn_mfma_f32_16x16x32_bf16(afrg[0], bfrg[ct][0], c0, 0, 0, 0);
            c0 = __builtin_amdgcn_mfma_f32_16x16x32_bf16(afrg[1], bfrg[ct][1], c0, 0, 0, 0);
            acc[ct] = c0;
        }

        // epilogue into image cols 1..64 (C/D: col=lane&15, row=(l>>4)*4+reg)
        float* bufw = img + (i % 3) * TILEF;
        #pragma unroll
        for (int ct = 0; ct < 4; ++ct)
            #pragma unroll
            for (int rg = 0; rg < 4; ++rg)
                bufw[(kslot * 4 + rg) * DIMV + 1 + ct * 16 + lrow] = acc[ct][rg];
        // (col-0 dwords in the image keep their DMA-loaded x values)

        // contiguous NON-TEMPORAL stores via ext-vector fv4
        fv4* og = (fv4*)(ow + (size_t)i * TILEF);
        const fv4* iv = (const fv4*)bufw;
        #pragma unroll
        for (int p = 0; p < 4; ++p) {
            fv4 val = iv[p * 64 + l];
            __builtin_nontemporal_store(val, &og[p * 64 + l]);
        }
        if (l < 4) {
            fv4 val = iv[256 + l];
            __builtin_nontemporal_store(val, &og[256 + l]);
        }
    };

    // ---- prologue: tiles 0 and 1 in flight ----
    issue_loads(0);
    issue_loads(1);
    __builtin_amdgcn_sched_barrier(0);

#define TILE_STEP(I, VMSTR)                                   \
    do {                                                      \
        if ((I) + 2 < WTILES) issue_loads((I) + 2);           \
        __builtin_amdgcn_sched_barrier(0);                    \
        asm volatile("s_waitcnt " VMSTR ::: "memory");        \
        __builtin_amdgcn_sched_barrier(0);                    \
        do_tile(I);                                           \
    } while (0)

    TILE_STEP(0, "vmcnt(10)");   // newer: L(1)=5, L(2)=5
    TILE_STEP(1, "vmcnt(15)");   // newer: L(2)=5, S(0)=5, L(3)=5
    TILE_STEP(2, "vmcnt(20)");   // newer: S(0)+L(3)+S(1)+L(4)
    TILE_STEP(3, "vmcnt(20)");
    TILE_STEP(4, "vmcnt(20)");
    TILE_STEP(5, "vmcnt(20)");
    TILE_STEP(6, "vmcnt(15)");   // newer: S(4)+L(7)+S(5)
    TILE_STEP(7, "vmcnt(10)");   // newer: S(5)+S(6)
#undef TILE_STEP
}

extern "C" void kernel_launch(void* const* d_in, const int* in_sizes, int n_in,
                              void* d_out, int out_size, void* d_ws, size_t ws_size,
                              hipStream_t stream) {
    const float* x         = (const float*)d_in[0];
    const int*   r_idx     = (const int*)d_in[1];
    const float* emb       = (const float*)d_in[2];
    const float* flip_sign = (const float*)d_in[3];
    float* out = (float*)d_out;
    unsigned short* WgT = (unsigned short*)d_ws;   // 512*64*64*2 = 4 MB bf16 W^T

    build_W<<<NUM_EMB, 256, 0, stream>>>(emb, flip_sign, r_idx, WgT, out);
    apply_W<<<GRID_APPLY, 256, 0, stream>>>(x, r_idx, WgT, out);
}